// Round 10
// baseline (14872.705 us; speedup 1.0000x reference)
//
#include <hip/hip_runtime.h>

typedef __attribute__((ext_vector_type(8))) short short8;
typedef __attribute__((ext_vector_type(4))) float f32x4;
typedef __attribute__((ext_vector_type(2))) unsigned long long u64x2;

constexpr int Bsz = 128;   // batch
constexpr int Tlen = 512;  // seq len
constexpr int Hd = 1024;   // hidden
constexpr int K0 = 1024;   // L0 ring K (h only; x via P table)
constexpr int K1 = 2048;   // L1 ring K = [h1 | y0]
constexpr int BK = 128;    // K-chunk
constexpr int BKP = 136;   // padded LDS row stride

constexpr int SM_A = 64 * BKP * 2;   // 17408 B per A buffer
constexpr int SM_B = 48 * BKP * 2;   // 13056 B per B buffer
constexpr int SM_TOT = 2 * SM_A + 2 * SM_B;  // 60928 B

__device__ __forceinline__ unsigned short f2b(float f) {
  unsigned int u = __float_as_uint(f);
  u = (u + 0x7FFFu + ((u >> 16) & 1u)) >> 16;
  return (unsigned short)u;
}
__device__ __forceinline__ float b2f(unsigned short u) {
  return __uint_as_float(((unsigned int)u) << 16);
}
__device__ __forceinline__ unsigned long long aload64(const unsigned long long* p) {
  return __hip_atomic_load(p, __ATOMIC_RELAXED, __HIP_MEMORY_SCOPE_AGENT);
}
__device__ __forceinline__ unsigned int aload32(const unsigned int* p) {
  return __hip_atomic_load(p, __ATOMIC_RELAXED, __HIP_MEMORY_SCOPE_AGENT);
}
__device__ __forceinline__ void astore32(unsigned int* p, unsigned int v) {
  __hip_atomic_store(p, v, __ATOMIC_RELAXED, __HIP_MEMORY_SCOPE_AGENT);
}

__global__ void __launch_bounds__(256, 1) gru_persist(
    const int* __restrict__ src,
    const float* __restrict__ P,              // [512][3072] fp32
    const unsigned short* __restrict__ Whh0b, // [3072][1024] bf16
    const unsigned short* __restrict__ Whh1b,
    const unsigned short* __restrict__ Wih1b,
    const float* __restrict__ bhh0,
    const float* __restrict__ bih1,
    const float* __restrict__ bhh1,
    float* __restrict__ dout,
    unsigned short* __restrict__ A0,
    unsigned short* __restrict__ A1,
    unsigned int* __restrict__ bar,    // [0]=barrier counter, [1..256]=slot claims
    int* __restrict__ taken)
{
  __shared__ __align__(16) unsigned char smem[SM_TOT];
  __shared__ int s_work;

  const int tid = threadIdx.x;

  // ---- XCD-affinity work claiming: prefer slots on own XCD so each XCD's
  // weight slice (2.36 MB) stays L2-resident across all rounds.
  if (tid == 0) {
    unsigned int xcc;
    asm volatile("s_getreg_b32 %0, hwreg(HW_REG_XCC_ID)" : "=s"(xcc));
    const int pref = ((int)(xcc & 7u)) * 32;
    int got = -1;
    for (int j = 0; j < 256; ++j) {
      const int idx = (pref + j) & 255;
      int expected = 0;
      if (__hip_atomic_compare_exchange_strong(&taken[idx], &expected, 1,
              __ATOMIC_RELAXED, __ATOMIC_RELAXED, __HIP_MEMORY_SCOPE_AGENT)) {
        got = idx; break;
      }
    }
    s_work = got;
  }
  __syncthreads();
  const int work = s_work;
  const int xcd_w = work >> 5;          // 0..7
  const int slot = work & 31;
  const int layer = (slot >> 4) & 1;
  const int c = xcd_w * 8 + ((slot >> 1) & 7);   // gate-triple 0..63
  const int mh = slot & 1;
  const int R0 = mh * 64;
  const int J0 = c * 16;

  const int Ksz = layer ? K1 : K0;
  const int nch = Ksz / BK;             // 8 or 16
  unsigned short* Ab = layer ? A1 : A0;
  const unsigned short* Wh = layer ? Whh1b : Whh0b;
  const unsigned short* Wx = Wih1b;

  const int w = tid >> 6;
  const int lane = tid & 63;
  const int lrow = lane >> 4;
  const int lcol = lane & 15;

  const int col = J0 + lcol;
  const float* bhh = layer ? bhh1 : bhh0;
  const float bhr = bhh[col], bhz = bhh[1024 + col], bhn = bhh[2048 + col];
  const float bir = layer ? bih1[col] : 0.f;
  const float biz = layer ? bih1[1024 + col] : 0.f;
  const float bin = layer ? bih1[2048 + col] : 0.f;

  for (int r = 0; r <= 512; ++r) {
    const bool active = layer ? (r >= 1) : (r < 512);
    if (active) {
      const bool first = layer ? (r == 1) : (r == 0);
      const int par = r & 1;
      const unsigned short* Acur = Ab + par * (Bsz * Ksz);
      unsigned short* Anext = Ab + (par ^ 1) * (Bsz * Ksz);

      // ---- epilogue operand prefetch (wave 0): P rows + h_old, hidden under GEMM
      float gpr[4][4], gpz[4][4], gpn[4][4], ghold[4][4];
      if (w == 0) {
#pragma unroll
        for (int f = 0; f < 4; ++f) {
#pragma unroll
          for (int i = 0; i < 4; ++i) {
            const int row = R0 + f * 16 + lrow * 4 + i;
            if (layer == 0) {
              const int sv = src[row * Tlen + r];
              const float* pr = P + sv * 3072 + col;
              gpr[f][i] = pr[0]; gpz[f][i] = pr[1024]; gpn[f][i] = pr[2048];
            } else {
              gpr[f][i] = bir; gpz[f][i] = biz; gpn[f][i] = bin;
            }
            if (first) {
              ghold[f][i] = 0.f;
            } else {
              const unsigned int hv = aload32((const unsigned int*)(
                  Acur + row * Ksz + J0 + (lcol & ~1)));
              ghold[f][i] = b2f((lcol & 1) ? (unsigned short)(hv >> 16)
                                           : (unsigned short)(hv & 0xFFFF));
            }
          }
        }
      }

      f32x4 ar[4], az[4], anh[4], anx[4];
#pragma unroll
      for (int f = 0; f < 4; ++f) {
        ar[f] = (f32x4){0.f, 0.f, 0.f, 0.f};
        az[f] = (f32x4){0.f, 0.f, 0.f, 0.f};
        anh[f] = (f32x4){0.f, 0.f, 0.f, 0.f};
        anx[f] = (f32x4){0.f, 0.f, 0.f, 0.f};
      }

      const int ch0 = first ? (layer ? 8 : nch) : 0;

      if (ch0 < nch) {
        u64x2 pa[4];          // ring A-tile via LLC-coherent b64 atomic loads
        short8 pb[3];         // weights via normal (L2-resident) loads
        auto ld = [&](int ch) {
          const int k0 = ch * BK;
#pragma unroll
          for (int s = 0; s < 4; ++s) {
            const int idx = tid + s * 256, rowi = idx >> 4, k8 = idx & 15;
            const unsigned long long* ap = (const unsigned long long*)(
                Acur + (R0 + rowi) * Ksz + k0 + k8 * 8);
            pa[s][0] = aload64(ap);
            pa[s][1] = aload64(ap + 1);
          }
#pragma unroll
          for (int s = 0; s < 3; ++s) {
            const int idx = tid + s * 256, tr = idx >> 4, k8 = idx & 15;
            const int wrow = (tr >> 4) * 1024 + J0 + (tr & 15);
            const unsigned short* gp = (k0 < 1024)
                ? (Wh + wrow * 1024 + k0 + k8 * 8)
                : (Wx + wrow * 1024 + (k0 - 1024) + k8 * 8);
            pb[s] = *(const short8*)gp;
          }
        };
        auto st = [&](int b) {
          unsigned short* sA = (unsigned short*)(smem + b * SM_A);
          unsigned short* sB = (unsigned short*)(smem + 2 * SM_A + b * SM_B);
#pragma unroll
          for (int s = 0; s < 4; ++s) {
            const int idx = tid + s * 256, rowi = idx >> 4, k8 = idx & 15;
            *(u64x2*)(sA + rowi * BKP + k8 * 8) = pa[s];
          }
#pragma unroll
          for (int s = 0; s < 3; ++s) {
            const int idx = tid + s * 256, tr = idx >> 4, k8 = idx & 15;
            *(short8*)(sB + tr * BKP + k8 * 8) = pb[s];
          }
        };

        ld(ch0); st(0);
        __syncthreads();

        for (int ch = ch0; ch < nch; ++ch) {
          const int b = (ch - ch0) & 1;
          const bool pf = (ch + 1 < nch);
          if (pf) ld(ch + 1);

          const unsigned short* sA = (const unsigned short*)(smem + b * SM_A);
          const unsigned short* sB = (const unsigned short*)(smem + 2 * SM_A + b * SM_B);
          const int ke = w * 32 + lrow * 8;
          short8 bfr = *(const short8*)(sB + (lcol) * BKP + ke);
          short8 bfz = *(const short8*)(sB + (16 + lcol) * BKP + ke);
          short8 bfn = *(const short8*)(sB + (32 + lcol) * BKP + ke);
          const bool hp = (ch * BK) < 1024;
#pragma unroll
          for (int f = 0; f < 4; ++f) {
            short8 a = *(const short8*)(sA + (f * 16 + lcol) * BKP + ke);
            ar[f] = __builtin_amdgcn_mfma_f32_16x16x32_bf16(a, bfr, ar[f], 0, 0, 0);
            az[f] = __builtin_amdgcn_mfma_f32_16x16x32_bf16(a, bfz, az[f], 0, 0, 0);
            if (hp) anh[f] = __builtin_amdgcn_mfma_f32_16x16x32_bf16(a, bfn, anh[f], 0, 0, 0);
            else    anx[f] = __builtin_amdgcn_mfma_f32_16x16x32_bf16(a, bfn, anx[f], 0, 0, 0);
          }
          if (pf) st(b ^ 1);
          __syncthreads();
        }
      }

      // ---- cross-wave reduction
      f32x4* red = (f32x4*)smem;
      if (w > 0) {
        f32x4* dst = red + (w - 1) * 1024;
#pragma unroll
        for (int f = 0; f < 4; ++f) {
          dst[(0 * 4 + f) * 64 + lane] = ar[f];
          dst[(1 * 4 + f) * 64 + lane] = az[f];
          dst[(2 * 4 + f) * 64 + lane] = anh[f];
          dst[(3 * 4 + f) * 64 + lane] = anx[f];
        }
      }
      __syncthreads();
      if (w == 0) {
#pragma unroll
        for (int f = 0; f < 4; ++f) {
          ar[f]  += red[(0*4+f)*64+lane] + red[1024+(0*4+f)*64+lane] + red[2048+(0*4+f)*64+lane];
          az[f]  += red[(1*4+f)*64+lane] + red[1024+(1*4+f)*64+lane] + red[2048+(1*4+f)*64+lane];
          anh[f] += red[(2*4+f)*64+lane] + red[1024+(2*4+f)*64+lane] + red[2048+(2*4+f)*64+lane];
          anx[f] += red[(3*4+f)*64+lane] + red[1024+(3*4+f)*64+lane] + red[2048+(3*4+f)*64+lane];
        }

        const bool lastw = layer ? (r == 512) : (r == 511);
#pragma unroll
        for (int f = 0; f < 4; ++f) {
#pragma unroll
          for (int i = 0; i < 4; ++i) {
            const int row = R0 + f * 16 + lrow * 4 + i;
            float rg = ar[f][i] + gpr[f][i] + bhr;
            rg = 1.f / (1.f + __expf(-rg));
            float zg = az[f][i] + gpz[f][i] + bhz;
            zg = 1.f / (1.f + __expf(-zg));
            const float ng = tanhf((anx[f][i] + gpn[f][i]) + rg * (anh[f][i] + bhn));
            const float hnew = (1.f - zg) * ng + zg * ghold[f][i];
            const unsigned int hb = (unsigned int)f2b(hnew);
            const unsigned int nb = (unsigned int)__shfl_down((int)hb, 1, 64);
            if ((lcol & 1) == 0) {
              const unsigned int pv = hb | (nb << 16);
              astore32((unsigned int*)(Anext + row * Ksz + J0 + lcol), pv);
              if (layer == 0)
                astore32((unsigned int*)(A1 + (par ^ 1) * (Bsz * K1) +
                                         row * K1 + 1024 + J0 + lcol), pv);
            }
            if (lastw) dout[layer * (Bsz * Hd) + row * Hd + col] = hnew;
          }
        }
      }
    }

    // ---- grid barrier: NO cache maintenance (ring data is LLC-coherent already)
    if (r < 512) {
      __syncthreads();
      if (tid == 0) {
        __atomic_signal_fence(__ATOMIC_SEQ_CST);
        __builtin_amdgcn_s_waitcnt(0);   // ring stores retired to LLC
        __hip_atomic_fetch_add(bar, 1u, __ATOMIC_RELAXED, __HIP_MEMORY_SCOPE_AGENT);
        const unsigned tgt = 256u * (unsigned)(r + 1);
        while (__hip_atomic_load(bar, __ATOMIC_RELAXED, __HIP_MEMORY_SCOPE_AGENT) < tgt)
          __builtin_amdgcn_s_sleep(8);
        __atomic_signal_fence(__ATOMIC_SEQ_CST);
      }
      __syncthreads();
    }
  }
}

// ---------------- prep kernels ----------------
__global__ void __launch_bounds__(256) cvt_k(const float* __restrict__ s,
                                            unsigned short* __restrict__ d, int n) {
  const int i = (blockIdx.x * 256 + threadIdx.x) * 8;
  if (i >= n) return;
  const float4 a = *(const float4*)(s + i);
  const float4 b = *(const float4*)(s + i + 4);
  short8 o;
  o[0] = (short)f2b(a.x); o[1] = (short)f2b(a.y);
  o[2] = (short)f2b(a.z); o[3] = (short)f2b(a.w);
  o[4] = (short)f2b(b.x); o[5] = (short)f2b(b.y);
  o[6] = (short)f2b(b.z); o[7] = (short)f2b(b.w);
  *(short8*)(d + i) = o;
}

__global__ void __launch_bounds__(256) pemb_k(const float* __restrict__ emb,
                                             const float* __restrict__ wih0,
                                             const float* __restrict__ bih0,
                                             float* __restrict__ P) {
  __shared__ float se[64 * 64];
  const int g = blockIdx.x * 256 + threadIdx.x;
  const int v0 = blockIdx.y * 64;
  float acc[64];
#pragma unroll
  for (int i = 0; i < 64; ++i) acc[i] = 0.f;
  for (int kb = 0; kb < 8; ++kb) {
    __syncthreads();
#pragma unroll
    for (int s = 0; s < 4; ++s) {
      const int idx = threadIdx.x + s * 256;
      const int vv = idx >> 4, k4 = (idx & 15) * 4;
      *(float4*)(se + vv * 64 + k4) =
          *(const float4*)(emb + (v0 + vv) * 512 + kb * 64 + k4);
    }
    __syncthreads();
    float4 wv[16];
#pragma unroll
    for (int j = 0; j < 16; ++j)
      wv[j] = *(const float4*)(wih0 + g * 512 + kb * 64 + j * 4);
    for (int vv = 0; vv < 64; ++vv) {
      const float* er = se + vv * 64;
      float s0 = acc[vv];
#pragma unroll
      for (int j = 0; j < 16; ++j) {
        const float4 e = *(const float4*)(er + j * 4);
        s0 += wv[j].x * e.x + wv[j].y * e.y + wv[j].z * e.z + wv[j].w * e.w;
      }
      acc[vv] = s0;
    }
  }
  const float bb = bih0[g];
  for (int vv = 0; vv < 64; ++vv) P[(v0 + vv) * 3072 + g] = acc[vv] + bb;
}

__global__ void zero_k(unsigned int* bar, int* taken) {
  const int i = threadIdx.x;           // 0..255
  if (i == 0) *bar = 0u;
  taken[i] = 0;
}

extern "C" void kernel_launch(void* const* d_in, const int* in_sizes, int n_in,
                              void* d_out, int out_size, void* d_ws, size_t ws_size,
                              hipStream_t stream) {
  const int* src = (const int*)d_in[0];
  const float* emb = (const float*)d_in[1];
  const float* wih0 = (const float*)d_in[2];
  const float* whh0 = (const float*)d_in[3];
  const float* bih0 = (const float*)d_in[4];
  const float* bhh0 = (const float*)d_in[5];
  const float* wih1 = (const float*)d_in[6];
  const float* whh1 = (const float*)d_in[7];
  const float* bih1 = (const float*)d_in[8];
  const float* bhh1 = (const float*)d_in[9];
  float* dout = (float*)d_out;

  char* p = (char*)d_ws;
  unsigned short* A0 = (unsigned short*)p;                       // 524288 B
  unsigned short* A1 = (unsigned short*)(p + 524288);            // 1048576 B
  unsigned short* Whh0b = (unsigned short*)(p + 1572864);        // 6291456 B
  unsigned short* Whh1b = (unsigned short*)(p + 7864320);        // 6291456 B
  unsigned short* Wih1b = (unsigned short*)(p + 14155776);       // 6291456 B
  float* P = (float*)(p + 20447232);                             // 6291456 B
  unsigned int* bar = (unsigned int*)(p + 26738688);             // 64 B
  int* taken = (int*)(p + 26738752);                             // 1024 B
  // total ws use: ~25.5 MB

  constexpr int NW = 3072 * 1024;
  hipLaunchKernelGGL(cvt_k, dim3(NW / (256 * 8)), dim3(256), 0, stream, whh0, Whh0b, NW);
  hipLaunchKernelGGL(cvt_k, dim3(NW / (256 * 8)), dim3(256), 0, stream, whh1, Whh1b, NW);
  hipLaunchKernelGGL(cvt_k, dim3(NW / (256 * 8)), dim3(256), 0, stream, wih1, Wih1b, NW);
  hipLaunchKernelGGL(pemb_k, dim3(12, 8), dim3(256), 0, stream, emb, wih0, bih0, P);
  hipLaunchKernelGGL(zero_k, dim3(1), dim3(256), 0, stream, bar, taken);

  hipLaunchKernelGGL(gru_persist, dim3(256), dim3(256), 0, stream,
                     src, P, Whh0b, Whh1b, Wih1b, bhh0, bih1, bhh1,
                     dout, A0, A1, bar, taken);
}

// Round 11
// 12897.058 us; speedup vs baseline: 1.1532x; 1.1532x over previous
//
#include <hip/hip_runtime.h>

typedef __attribute__((ext_vector_type(8))) short short8;
typedef __attribute__((ext_vector_type(4))) float f32x4;
typedef __attribute__((ext_vector_type(2))) unsigned long long u64x2;

constexpr int Bsz = 128;   // batch
constexpr int Tlen = 512;  // seq len
constexpr int Hd = 1024;   // hidden
constexpr int K0 = 1024;   // L0 ring K (h only; x via P table)
constexpr int K1 = 2048;   // L1 ring K = [h1 | y0]
constexpr int BK = 128;    // K-chunk
constexpr int BKP = 136;   // padded LDS row stride

constexpr int SM_A = 64 * BKP * 2;   // 17408 B per A buffer
constexpr int SM_B = 48 * BKP * 2;   // 13056 B per B buffer
constexpr int SM_TOT = 2 * SM_A + 2 * SM_B;  // 60928 B

__device__ __forceinline__ unsigned short f2b(float f) {
  unsigned int u = __float_as_uint(f);
  u = (u + 0x7FFFu + ((u >> 16) & 1u)) >> 16;
  return (unsigned short)u;
}
__device__ __forceinline__ float b2f(unsigned short u) {
  return __uint_as_float(((unsigned int)u) << 16);
}
__device__ __forceinline__ unsigned long long aload64(const unsigned long long* p) {
  return __hip_atomic_load(p, __ATOMIC_RELAXED, __HIP_MEMORY_SCOPE_AGENT);
}
__device__ __forceinline__ unsigned int aload32(const unsigned int* p) {
  return __hip_atomic_load(p, __ATOMIC_RELAXED, __HIP_MEMORY_SCOPE_AGENT);
}
__device__ __forceinline__ void astore32(unsigned int* p, unsigned int v) {
  __hip_atomic_store(p, v, __ATOMIC_RELAXED, __HIP_MEMORY_SCOPE_AGENT);
}

__global__ void __launch_bounds__(256, 1) gru_persist(
    const int* __restrict__ src,
    const float* __restrict__ P,              // [512][3072] fp32
    const unsigned short* __restrict__ Whh0b, // [3072][1024] bf16
    const unsigned short* __restrict__ Whh1b,
    const unsigned short* __restrict__ Wih1b,
    const float* __restrict__ bhh0,
    const float* __restrict__ bih1,
    const float* __restrict__ bhh1,
    float* __restrict__ dout,
    unsigned short* __restrict__ A0,
    unsigned short* __restrict__ A1,
    unsigned int* __restrict__ flags,  // [256] round flags, one 64B line each
    int* __restrict__ taken)
{
  __shared__ __align__(16) unsigned char smem[SM_TOT];
  __shared__ int s_work;

  const int tid = threadIdx.x;

  // ---- XCD-affinity work claiming: per-XCD weight slice stays L2-resident.
  if (tid == 0) {
    unsigned int xcc;
    asm volatile("s_getreg_b32 %0, hwreg(HW_REG_XCC_ID)" : "=s"(xcc));
    const int pref = ((int)(xcc & 7u)) * 32;
    int got = -1;
    for (int j = 0; j < 256; ++j) {
      const int idx = (pref + j) & 255;
      int expected = 0;
      if (__hip_atomic_compare_exchange_strong(&taken[idx], &expected, 1,
              __ATOMIC_RELAXED, __ATOMIC_RELAXED, __HIP_MEMORY_SCOPE_AGENT)) {
        got = idx; break;
      }
    }
    s_work = got;
  }
  __syncthreads();
  const int work = s_work;
  const int xcd_w = work >> 5;          // 0..7
  const int slot = work & 31;
  const int layer = (slot >> 4) & 1;
  const int c = xcd_w * 8 + ((slot >> 1) & 7);   // gate-triple 0..63
  const int mh = slot & 1;
  const int R0 = mh * 64;
  const int J0 = c * 16;

  const int Ksz = layer ? K1 : K0;
  const int nch = Ksz / BK;             // 8 or 16
  unsigned short* Ab = layer ? A1 : A0;
  const unsigned short* Wh = layer ? Whh1b : Whh0b;
  const unsigned short* Wx = Wih1b;

  const int w = tid >> 6;
  const int lane = tid & 63;
  const int lrow = lane >> 4;
  const int lcol = lane & 15;

  const int col = J0 + lcol;
  const float* bhh = layer ? bhh1 : bhh0;
  const float bhr = bhh[col], bhz = bhh[1024 + col], bhn = bhh[2048 + col];
  const float bir = layer ? bih1[col] : 0.f;
  const float biz = layer ? bih1[1024 + col] : 0.f;
  const float bin = layer ? bih1[2048 + col] : 0.f;

  for (int r = 0; r <= 512; ++r) {
    const bool active = layer ? (r >= 1) : (r < 512);
    if (active) {
      const bool first = layer ? (r == 1) : (r == 0);
      const int par = r & 1;
      const unsigned short* Acur = Ab + par * (Bsz * Ksz);
      unsigned short* Anext = Ab + (par ^ 1) * (Bsz * Ksz);

      // ---- epilogue operand prefetch (wave 0): latency hides under GEMM
      float gpr[4][4], gpz[4][4], gpn[4][4], ghold[4][4];
      if (w == 0) {
#pragma unroll
        for (int f = 0; f < 4; ++f) {
#pragma unroll
          for (int i = 0; i < 4; ++i) {
            const int row = R0 + f * 16 + lrow * 4 + i;
            if (layer == 0) {
              const int sv = src[row * Tlen + r];
              const float* pr = P + sv * 3072 + col;
              gpr[f][i] = pr[0]; gpz[f][i] = pr[1024]; gpn[f][i] = pr[2048];
            } else {
              gpr[f][i] = bir; gpz[f][i] = biz; gpn[f][i] = bin;
            }
            if (first) {
              ghold[f][i] = 0.f;
            } else {
              const unsigned int hv = aload32((const unsigned int*)(
                  Acur + row * Ksz + J0 + (lcol & ~1)));
              ghold[f][i] = b2f((lcol & 1) ? (unsigned short)(hv >> 16)
                                           : (unsigned short)(hv & 0xFFFF));
            }
          }
        }
      }

      f32x4 ar[4], az[4], anh[4], anx[4];
#pragma unroll
      for (int f = 0; f < 4; ++f) {
        ar[f] = (f32x4){0.f, 0.f, 0.f, 0.f};
        az[f] = (f32x4){0.f, 0.f, 0.f, 0.f};
        anh[f] = (f32x4){0.f, 0.f, 0.f, 0.f};
        anx[f] = (f32x4){0.f, 0.f, 0.f, 0.f};
      }

      const int ch0 = first ? (layer ? 8 : nch) : 0;

      if (ch0 < nch) {
        u64x2 pa[4];          // ring A-tile via LLC-coherent b64 atomic loads
        short8 pb[3];         // weights via normal (L2-resident) loads
        auto ld = [&](int ch) {
          const int k0 = ch * BK;
#pragma unroll
          for (int s = 0; s < 4; ++s) {
            const int idx = tid + s * 256, rowi = idx >> 4, k8 = idx & 15;
            const unsigned long long* ap = (const unsigned long long*)(
                Acur + (R0 + rowi) * Ksz + k0 + k8 * 8);
            pa[s][0] = aload64(ap);
            pa[s][1] = aload64(ap + 1);
          }
#pragma unroll
          for (int s = 0; s < 3; ++s) {
            const int idx = tid + s * 256, tr = idx >> 4, k8 = idx & 15;
            const int wrow = (tr >> 4) * 1024 + J0 + (tr & 15);
            const unsigned short* gp = (k0 < 1024)
                ? (Wh + wrow * 1024 + k0 + k8 * 8)
                : (Wx + wrow * 1024 + (k0 - 1024) + k8 * 8);
            pb[s] = *(const short8*)gp;
          }
        };
        auto st = [&](int b) {
          unsigned short* sA = (unsigned short*)(smem + b * SM_A);
          unsigned short* sB = (unsigned short*)(smem + 2 * SM_A + b * SM_B);
#pragma unroll
          for (int s = 0; s < 4; ++s) {
            const int idx = tid + s * 256, rowi = idx >> 4, k8 = idx & 15;
            *(u64x2*)(sA + rowi * BKP + k8 * 8) = pa[s];
          }
#pragma unroll
          for (int s = 0; s < 3; ++s) {
            const int idx = tid + s * 256, tr = idx >> 4, k8 = idx & 15;
            *(short8*)(sB + tr * BKP + k8 * 8) = pb[s];
          }
        };

        ld(ch0); st(0);
        __syncthreads();

        for (int ch = ch0; ch < nch; ++ch) {
          const int b = (ch - ch0) & 1;
          const bool pf = (ch + 1 < nch);
          if (pf) ld(ch + 1);

          const unsigned short* sA = (const unsigned short*)(smem + b * SM_A);
          const unsigned short* sB = (const unsigned short*)(smem + 2 * SM_A + b * SM_B);
          const int ke = w * 32 + lrow * 8;
          short8 bfr = *(const short8*)(sB + (lcol) * BKP + ke);
          short8 bfz = *(const short8*)(sB + (16 + lcol) * BKP + ke);
          short8 bfn = *(const short8*)(sB + (32 + lcol) * BKP + ke);
          const bool hp = (ch * BK) < 1024;
#pragma unroll
          for (int f = 0; f < 4; ++f) {
            short8 a = *(const short8*)(sA + (f * 16 + lcol) * BKP + ke);
            ar[f] = __builtin_amdgcn_mfma_f32_16x16x32_bf16(a, bfr, ar[f], 0, 0, 0);
            az[f] = __builtin_amdgcn_mfma_f32_16x16x32_bf16(a, bfz, az[f], 0, 0, 0);
            if (hp) anh[f] = __builtin_amdgcn_mfma_f32_16x16x32_bf16(a, bfn, anh[f], 0, 0, 0);
            else    anx[f] = __builtin_amdgcn_mfma_f32_16x16x32_bf16(a, bfn, anx[f], 0, 0, 0);
          }
          if (pf) st(b ^ 1);
          __syncthreads();
        }
      }

      // ---- cross-wave reduction
      f32x4* red = (f32x4*)smem;
      if (w > 0) {
        f32x4* dst = red + (w - 1) * 1024;
#pragma unroll
        for (int f = 0; f < 4; ++f) {
          dst[(0 * 4 + f) * 64 + lane] = ar[f];
          dst[(1 * 4 + f) * 64 + lane] = az[f];
          dst[(2 * 4 + f) * 64 + lane] = anh[f];
          dst[(3 * 4 + f) * 64 + lane] = anx[f];
        }
      }
      __syncthreads();
      if (w == 0) {
#pragma unroll
        for (int f = 0; f < 4; ++f) {
          ar[f]  += red[(0*4+f)*64+lane] + red[1024+(0*4+f)*64+lane] + red[2048+(0*4+f)*64+lane];
          az[f]  += red[(1*4+f)*64+lane] + red[1024+(1*4+f)*64+lane] + red[2048+(1*4+f)*64+lane];
          anh[f] += red[(2*4+f)*64+lane] + red[1024+(2*4+f)*64+lane] + red[2048+(2*4+f)*64+lane];
          anx[f] += red[(3*4+f)*64+lane] + red[1024+(3*4+f)*64+lane] + red[2048+(3*4+f)*64+lane];
        }

        const bool lastw = layer ? (r == 512) : (r == 511);
#pragma unroll
        for (int f = 0; f < 4; ++f) {
#pragma unroll
          for (int i = 0; i < 4; ++i) {
            const int row = R0 + f * 16 + lrow * 4 + i;
            float rg = ar[f][i] + gpr[f][i] + bhr;
            rg = 1.f / (1.f + __expf(-rg));
            float zg = az[f][i] + gpz[f][i] + bhz;
            zg = 1.f / (1.f + __expf(-zg));
            const float ng = tanhf((anx[f][i] + gpn[f][i]) + rg * (anh[f][i] + bhn));
            const float hnew = (1.f - zg) * ng + zg * ghold[f][i];
            const unsigned int hb = (unsigned int)f2b(hnew);
            const unsigned int nb = (unsigned int)__shfl_down((int)hb, 1, 64);
            if ((lcol & 1) == 0) {
              const unsigned int pv = hb | (nb << 16);
              astore32((unsigned int*)(Anext + row * Ksz + J0 + lcol), pv);
              if (layer == 0)
                astore32((unsigned int*)(A1 + (par ^ 1) * (Bsz * K1) +
                                         row * K1 + 1024 + J0 + lcol), pv);
            }
            if (lastw) dout[layer * (Bsz * Hd) + row * Hd + col] = hnew;
          }
        }
      }
    }

    // ---- grid barrier v2: per-block flag store (own 64B line, NO RMW) +
    // lane-parallel poll of all 256 flags. Serialization O(1) vs O(256).
    if (r < 512) {
      __syncthreads();   // all waves' ring stores drained to LLC (vmcnt0 before s_barrier)
      if (w == 0) {
        const unsigned tgt = (unsigned)(r + 1);
        if (lane == 0) astore32(&flags[(unsigned)blockIdx.x * 16u], tgt);
        for (;;) {
          const unsigned m0 = aload32(&flags[(unsigned)(lane)       * 16u]);
          const unsigned m1 = aload32(&flags[(unsigned)(lane + 64)  * 16u]);
          const unsigned m2 = aload32(&flags[(unsigned)(lane + 128) * 16u]);
          const unsigned m3 = aload32(&flags[(unsigned)(lane + 192) * 16u]);
          if (__all(m0 >= tgt && m1 >= tgt && m2 >= tgt && m3 >= tgt)) break;
          __builtin_amdgcn_s_sleep(2);
        }
      }
      __syncthreads();
    }
  }
}

// ---------------- prep kernels ----------------
__global__ void __launch_bounds__(256) cvt_k(const float* __restrict__ s,
                                            unsigned short* __restrict__ d, int n) {
  const int i = (blockIdx.x * 256 + threadIdx.x) * 8;
  if (i >= n) return;
  const float4 a = *(const float4*)(s + i);
  const float4 b = *(const float4*)(s + i + 4);
  short8 o;
  o[0] = (short)f2b(a.x); o[1] = (short)f2b(a.y);
  o[2] = (short)f2b(a.z); o[3] = (short)f2b(a.w);
  o[4] = (short)f2b(b.x); o[5] = (short)f2b(b.y);
  o[6] = (short)f2b(b.z); o[7] = (short)f2b(b.w);
  *(short8*)(d + i) = o;
}

__global__ void __launch_bounds__(256) pemb_k(const float* __restrict__ emb,
                                             const float* __restrict__ wih0,
                                             const float* __restrict__ bih0,
                                             float* __restrict__ P) {
  __shared__ float se[64 * 64];
  const int g = blockIdx.x * 256 + threadIdx.x;
  const int v0 = blockIdx.y * 64;
  float acc[64];
#pragma unroll
  for (int i = 0; i < 64; ++i) acc[i] = 0.f;
  for (int kb = 0; kb < 8; ++kb) {
    __syncthreads();
#pragma unroll
    for (int s = 0; s < 4; ++s) {
      const int idx = threadIdx.x + s * 256;
      const int vv = idx >> 4, k4 = (idx & 15) * 4;
      *(float4*)(se + vv * 64 + k4) =
          *(const float4*)(emb + (v0 + vv) * 512 + kb * 64 + k4);
    }
    __syncthreads();
    float4 wv[16];
#pragma unroll
    for (int j = 0; j < 16; ++j)
      wv[j] = *(const float4*)(wih0 + g * 512 + kb * 64 + j * 4);
    for (int vv = 0; vv < 64; ++vv) {
      const float* er = se + vv * 64;
      float s0 = acc[vv];
#pragma unroll
      for (int j = 0; j < 16; ++j) {
        const float4 e = *(const float4*)(er + j * 4);
        s0 += wv[j].x * e.x + wv[j].y * e.y + wv[j].z * e.z + wv[j].w * e.w;
      }
      acc[vv] = s0;
    }
  }
  const float bb = bih0[g];
  for (int vv = 0; vv < 64; ++vv) P[(v0 + vv) * 3072 + g] = acc[vv] + bb;
}

__global__ void zero_k(unsigned int* flags, int* taken) {
  const int i = threadIdx.x;           // 0..255
  for (int j = 0; j < 16; ++j) flags[i * 16 + j] = 0u;
  taken[i] = 0;
}

extern "C" void kernel_launch(void* const* d_in, const int* in_sizes, int n_in,
                              void* d_out, int out_size, void* d_ws, size_t ws_size,
                              hipStream_t stream) {
  const int* src = (const int*)d_in[0];
  const float* emb = (const float*)d_in[1];
  const float* wih0 = (const float*)d_in[2];
  const float* whh0 = (const float*)d_in[3];
  const float* bih0 = (const float*)d_in[4];
  const float* bhh0 = (const float*)d_in[5];
  const float* wih1 = (const float*)d_in[6];
  const float* whh1 = (const float*)d_in[7];
  const float* bih1 = (const float*)d_in[8];
  const float* bhh1 = (const float*)d_in[9];
  float* dout = (float*)d_out;

  char* p = (char*)d_ws;
  unsigned short* A0 = (unsigned short*)p;                       // 524288 B
  unsigned short* A1 = (unsigned short*)(p + 524288);            // 1048576 B
  unsigned short* Whh0b = (unsigned short*)(p + 1572864);        // 6291456 B
  unsigned short* Whh1b = (unsigned short*)(p + 7864320);        // 6291456 B
  unsigned short* Wih1b = (unsigned short*)(p + 14155776);       // 6291456 B
  float* P = (float*)(p + 20447232);                             // 6291456 B
  unsigned int* flags = (unsigned int*)(p + 26738688);           // 16384 B
  int* taken = (int*)(p + 26755072);                             // 1024 B
  // total ws use: ~25.5 MB

  constexpr int NW = 3072 * 1024;
  hipLaunchKernelGGL(cvt_k, dim3(NW / (256 * 8)), dim3(256), 0, stream, whh0, Whh0b, NW);
  hipLaunchKernelGGL(cvt_k, dim3(NW / (256 * 8)), dim3(256), 0, stream, whh1, Whh1b, NW);
  hipLaunchKernelGGL(cvt_k, dim3(NW / (256 * 8)), dim3(256), 0, stream, wih1, Wih1b, NW);
  hipLaunchKernelGGL(pemb_k, dim3(12, 8), dim3(256), 0, stream, emb, wih0, bih0, P);
  hipLaunchKernelGGL(zero_k, dim3(1), dim3(256), 0, stream, flags, taken);

  hipLaunchKernelGGL(gru_persist, dim3(256), dim3(256), 0, stream,
                     src, P, Whh0b, Whh1b, Wih1b, bhh0, bih1, bhh1,
                     dout, A0, A1, flags, taken);
}